// Round 1
// baseline (2063.920 us; speedup 1.0000x reference)
//
#include <hip/hip_runtime.h>

#define DEV __device__ __forceinline__

constexpr int L_ = 24, E_ = 1024, H_ = 16, HD_ = 64, S_ = 2048;
constexpr int NCHUNK = 256, CHUNK = 8;

// ws layout (float offsets)
constexpr int WS_HRES = 0;       // 1024  residual input h of current layer
constexpr int WS_QKV  = 1024;    // 3072  q|k|v
constexpr int WS_VALS = 4096;    // 1024  attention output vals
constexpr int WS_WO   = 5120;    // 1024  vals@Wo + bo
constexpr int WS_HA   = 6144;    // 1024  hA = LN1(h + wo_out)
constexpr int WS_FFT  = 7168;    // 1024  hA@W1 + b1 (pre-relu)
constexpr int WS_FFO  = 8192;    // 1024  relu(.)@W2 + b2
constexpr int WS_M    = 9216;    // NCHUNK*H
constexpr int WS_L    = 13312;   // NCHUNK*H
constexpr int WS_O    = 17408;   // NCHUNK*H*HD

DEV float dot4(float4 a, float4 b) { return a.x*b.x + a.y*b.y + a.z*b.z + a.w*b.w; }
DEV int nz4(float4 v) { return (v.x != 0.f) || (v.y != 0.f) || (v.z != 0.f) || (v.w != 0.f); }
DEV float4 upd(float4 o, float fs, float p, float4 v) {
  return make_float4(o.x*fs + p*v.x, o.y*fs + p*v.y, o.z*fs + p*v.z, o.w*fs + p*v.w);
}
// store 16 consecutive floats at p where (uintptr_t)p % 16 == 12
DEV void store16_off12(float* p, float4 a, float4 b, float4 c, float4 d) {
  p[0] = a.x;
  *(float4*)(p + 1) = make_float4(a.y, a.z, a.w, b.x);
  *(float4*)(p + 5) = make_float4(b.y, b.z, b.w, c.x);
  *(float4*)(p + 9) = make_float4(c.y, c.z, c.w, d.x);
  p[13] = d.y; p[14] = d.z; p[15] = d.w;
}

DEV float block_reduce_sum(float v, float* red) {
  int t = threadIdx.x;
  red[t] = v; __syncthreads();
  for (int st = 128; st > 0; st >>= 1) {
    if (t < st) red[t] += red[t + st];
    __syncthreads();
  }
  float r = red[0];
  __syncthreads();
  return r;
}

// y = LN(a + b) * sc + bi  into x_lds[1024]; ends with barrier
DEV void block_ln(const float* __restrict__ a, const float* __restrict__ b,
                  const float* __restrict__ sc, const float* __restrict__ bi,
                  float eps, float* x_lds, float* red) {
  int t = threadIdx.x;
  float v[4]; float s = 0.f;
#pragma unroll
  for (int j = 0; j < 4; ++j) {
    int idx = t * 4 + j;
    float x = a[idx] + (b ? b[idx] : 0.f);
    v[j] = x; s += x;
  }
  float mean = block_reduce_sum(s, red) * (1.f / E_);
  float vs = 0.f;
#pragma unroll
  for (int j = 0; j < 4; ++j) { float d = v[j] - mean; vs += d * d; }
  float var = block_reduce_sum(vs, red) * (1.f / E_);
  float rstd = rsqrtf(var + eps);
#pragma unroll
  for (int j = 0; j < 4; ++j) {
    int idx = t * 4 + j;
    x_lds[idx] = (v[j] - mean) * rstd * sc[idx] + bi[idx];
  }
  __syncthreads();
}

// split-K GEMV: out[col0..col0+64) += x(1024) @ W(1024 x E_) over rows [row0,row0+128)
DEV void gemv_acc(const float* __restrict__ W, const float* x_lds,
                  float* __restrict__ out, int col0, int row0, float4* racc) {
  int t = threadIdx.x;
  int c4 = t & 15, g = t >> 4;
  float4 acc = make_float4(0.f, 0.f, 0.f, 0.f);
  const float* Wp = W + (size_t)row0 * E_ + col0 + 4 * c4;
#pragma unroll
  for (int it = 0; it < 8; ++it) {
    int r = it * 16 + g;
    float xv = x_lds[row0 + r];
    float4 w = *(const float4*)(Wp + (size_t)r * E_);
    acc.x += xv * w.x; acc.y += xv * w.y; acc.z += xv * w.z; acc.w += xv * w.w;
  }
  racc[g * 16 + c4] = acc;
  __syncthreads();
  for (int st = 8; st > 0; st >>= 1) {
    if (g < st) {
      float4 o = racc[(g + st) * 16 + c4];
      acc.x += o.x; acc.y += o.y; acc.z += o.z; acc.w += o.w;
      racc[g * 16 + c4] = acc;
    }
    __syncthreads();
  }
  if (g == 0) {
    atomicAdd(&out[col0 + 4 * c4 + 0], acc.x);
    atomicAdd(&out[col0 + 4 * c4 + 1], acc.y);
    atomicAdd(&out[col0 + 4 * c4 + 2], acc.z);
    atomicAdd(&out[col0 + 4 * c4 + 3], acc.w);
  }
}

__global__ __launch_bounds__(256) void k_embed(
    const int* __restrict__ xi,
    const float* __restrict__ et, const float* __restrict__ eid,
    const float* __restrict__ ex, const float* __restrict__ ey,
    const float* __restrict__ etm,
    const float* __restrict__ lns, const float* __restrict__ lnb,
    const float* __restrict__ bq, const float* __restrict__ bk,
    const float* __restrict__ bv, float* __restrict__ ws) {
  __shared__ float red[256];
  int t = threadIdx.x;
  int i0 = xi[0], i1 = xi[1], i2 = xi[2], i3 = xi[3], i4 = xi[4];
  float v[4]; float s = 0.f;
#pragma unroll
  for (int j = 0; j < 4; ++j) {
    int idx = t * 4 + j;
    float val = et[i0 * E_ + idx] + eid[i1 * E_ + idx] + ex[i2 * E_ + idx]
              + ey[i3 * E_ + idx] + etm[i4 * E_ + idx];
    v[j] = val; s += val;
  }
  float mean = block_reduce_sum(s, red) * (1.f / E_);
  float vs = 0.f;
#pragma unroll
  for (int j = 0; j < 4; ++j) { float d = v[j] - mean; vs += d * d; }
  float var = block_reduce_sum(vs, red) * (1.f / E_);
  float rstd = rsqrtf(var + 1e-12f);
  float* hres = ws + WS_HRES; float* qkv = ws + WS_QKV;
#pragma unroll
  for (int j = 0; j < 4; ++j) {
    int idx = t * 4 + j;
    hres[idx] = (v[j] - mean) * rstd * lns[idx] + lnb[idx];
    qkv[idx]           = bq[idx];
    qkv[E_ + idx]      = bk[idx];
    qkv[2 * E_ + idx]  = bv[idx];
  }
}

// grid 384: 48 col-tiles (q|k|v) x 8 row-chunks
__global__ __launch_bounds__(256) void k_qkv(
    const float* __restrict__ Wq, const float* __restrict__ Wk,
    const float* __restrict__ Wv,
    const float* __restrict__ pl2s, const float* __restrict__ pl2b,
    float* __restrict__ ws, int layer, int first) {
  __shared__ float x_lds[E_];
  __shared__ float red[256];
  __shared__ float4 racc[256];
  int t = threadIdx.x;
  if (first) {
#pragma unroll
    for (int j = 0; j < 4; ++j) x_lds[t * 4 + j] = ws[WS_HRES + t * 4 + j];
    __syncthreads();
  } else {
    block_ln(ws + WS_HA, ws + WS_FFO, pl2s, pl2b, 1e-6f, x_lds, red);
    if (blockIdx.x == 0) {
#pragma unroll
      for (int j = 0; j < 4; ++j) ws[WS_HRES + t * 4 + j] = x_lds[t * 4 + j];
    }
  }
  int bx = blockIdx.x;
  int tile = bx % 48, rowc = bx / 48;
  int seg = tile >> 4;  // 0:q 1:k 2:v
  const float* W = (seg == 0 ? Wq : (seg == 1 ? Wk : Wv)) + (size_t)layer * E_ * E_;
  gemv_acc(W, x_lds, ws + WS_QKV + seg * E_, (tile & 15) * 64, rowc * 128, racc);
}

// grid NCHUNK(256) x 256 threads: flash attention chunk + fused cache shift
__global__ __launch_bounds__(256) void k_attn(
    const float* __restrict__ cache1, const float* __restrict__ cache2,
    float* __restrict__ oc1, float* __restrict__ oc2,
    float* __restrict__ ws, int layer) {
  const float* c1 = cache1 + (size_t)layer * S_ * E_;
  const float* c2 = cache2 + (size_t)layer * S_ * E_;
  float* o1 = oc1 + (size_t)layer * S_ * E_;
  float* o2 = oc2 + (size_t)layer * S_ * E_;
  const float* qbuf = ws + WS_QKV;
  const float* knew = ws + WS_QKV + E_;
  const float* vnew = ws + WS_QKV + 2 * E_;

  int t = threadIdx.x;
  int wv = t >> 6, lane = t & 63;
  int h = lane >> 2, g = lane & 3;
  int off = h * HD_ + g * 16;

  const float4* q4 = (const float4*)(qbuf + off);
  float4 qa = q4[0], qb = q4[1], qc = q4[2], qd = q4[3];

  float m = -1e30f, l = 0.f;
  float4 oa = make_float4(0,0,0,0), ob = oa, occ = oa, od = oa;

#pragma unroll
  for (int pp = 0; pp < 2; ++pp) {
    int sout = blockIdx.x * CHUNK + wv * 2 + pp;
    const float4 *kp, *vp;
    if (sout < S_ - 1) {
      kp = (const float4*)(c2 + (size_t)(sout + 1) * E_ + off);
      vp = (const float4*)(c1 + (size_t)(sout + 1) * E_ + off);
    } else {
      kp = (const float4*)(knew + off);
      vp = (const float4*)(vnew + off);
    }
    float4 ka = kp[0], kb = kp[1], kc = kp[2], kd = kp[3];
    float4 va = vp[0], vb = vp[1], vc = vp[2], vd = vp[3];
    float dot = dot4(qa, ka) + dot4(qb, kb) + dot4(qc, kc) + dot4(qd, kd);
    dot += __shfl_xor(dot, 1);
    dot += __shfl_xor(dot, 2);
    float score = dot * 0.125f;
    int nz = nz4(va) | nz4(vb) | nz4(vc) | nz4(vd);
    bool msk = (__ballot(nz) != 0ULL);
    if (msk) {
      float mn = fmaxf(m, score);
      float fs = __expf(m - mn);
      float p  = __expf(score - mn);
      l = l * fs + p;
      oa = upd(oa, fs, p, va); ob = upd(ob, fs, p, vb);
      occ = upd(occ, fs, p, vc); od = upd(od, fs, p, vd);
      m = mn;
    }
    store16_off12(o1 + (size_t)sout * E_ + off, va, vb, vc, vd);
    store16_off12(o2 + (size_t)sout * E_ + off, ka, kb, kc, kd);
  }

  __shared__ float sm[4][64];
  __shared__ float sl[4][64];
  __shared__ float4 so[4][64][4];
  sm[wv][lane] = m; sl[wv][lane] = l;
  so[wv][lane][0] = oa; so[wv][lane][1] = ob;
  so[wv][lane][2] = occ; so[wv][lane][3] = od;
  __syncthreads();
  if (t < 64) {
    float M = fmaxf(fmaxf(sm[0][lane], sm[1][lane]), fmaxf(sm[2][lane], sm[3][lane]));
    float Lt = 0.f;
    float4 ra = make_float4(0,0,0,0), rb = ra, rc = ra, rd = ra;
#pragma unroll
    for (int w = 0; w < 4; ++w) {
      float fs = __expf(sm[w][lane] - M);
      Lt += sl[w][lane] * fs;
      ra = upd(ra, 1.f, fs, so[w][lane][0]);
      rb = upd(rb, 1.f, fs, so[w][lane][1]);
      rc = upd(rc, 1.f, fs, so[w][lane][2]);
      rd = upd(rd, 1.f, fs, so[w][lane][3]);
    }
    int cidx = blockIdx.x * H_ + h;
    if (g == 0) { ws[WS_M + cidx] = M; ws[WS_L + cidx] = Lt; }
    float4* odst = (float4*)(ws + WS_O + (size_t)cidx * HD_ + g * 16);
    odst[0] = ra; odst[1] = rb; odst[2] = rc; odst[3] = rd;
  }
}

// grid H_(16) x 256: merge chunk partials -> vals; init wo_out with bo
__global__ __launch_bounds__(256) void k_combine(
    const float* __restrict__ bo, float* __restrict__ ws, int layer) {
  int h = blockIdx.x;
  int t = threadIdx.x, wv = t >> 6, lane = t & 63;
  const float* wm = ws + WS_M;
  const float* wl = ws + WS_L;
  const float* wo = ws + WS_O;
  const int CPW = NCHUNK / 4;
  float M = -1e30f;
#pragma unroll 8
  for (int c = wv * CPW; c < (wv + 1) * CPW; ++c)
    M = fmaxf(M, wm[(size_t)c * H_ + h]);
  float Lt = 0.f, O = 0.f;
#pragma unroll 4
  for (int c = wv * CPW; c < (wv + 1) * CPW; ++c) {
    float fs = __expf(wm[(size_t)c * H_ + h] - M);
    Lt += wl[(size_t)c * H_ + h] * fs;
    O  += fs * wo[((size_t)c * H_ + h) * HD_ + lane];
  }
  __shared__ float sm2[4], sl2[4], so2[4][64];
  if (lane == 0) { sm2[wv] = M; sl2[wv] = Lt; }
  so2[wv][lane] = O;
  __syncthreads();
  if (wv == 0) {
    float Mg = fmaxf(fmaxf(sm2[0], sm2[1]), fmaxf(sm2[2], sm2[3]));
    float Lg = 0.f, Og = 0.f;
#pragma unroll
    for (int w = 0; w < 4; ++w) {
      float fs = __expf(sm2[w] - Mg);
      Lg += sl2[w] * fs;
      Og += fs * so2[w][lane];
    }
    ws[WS_VALS + h * HD_ + lane] = Og / Lg;
    ws[WS_WO + h * HD_ + lane] = bo[(size_t)layer * E_ + h * HD_ + lane];
  }
}

// grid 128: wo_out += vals @ Wo ; block0 inits ff_t with b1
__global__ __launch_bounds__(256) void k_wo(
    const float* __restrict__ Wo, const float* __restrict__ b1,
    float* __restrict__ ws, int layer) {
  __shared__ float x_lds[E_];
  __shared__ float4 racc[256];
  int t = threadIdx.x;
#pragma unroll
  for (int j = 0; j < 4; ++j) x_lds[t * 4 + j] = ws[WS_VALS + t * 4 + j];
  __syncthreads();
  if (blockIdx.x == 0) {
#pragma unroll
    for (int j = 0; j < 4; ++j)
      ws[WS_FFT + t * 4 + j] = b1[(size_t)layer * E_ + t * 4 + j];
  }
  int tile = blockIdx.x & 15, rowc = blockIdx.x >> 4;
  gemv_acc(Wo + (size_t)layer * E_ * E_, x_lds, ws + WS_WO, tile * 64, rowc * 128, racc);
}

// grid 128: recompute hA = LN1(h_res + wo_out); ff_t += hA @ W1; block0 stores hA, inits ff_out=b2
__global__ __launch_bounds__(256) void k_w1(
    const float* __restrict__ W1, const float* __restrict__ ln1s,
    const float* __restrict__ ln1b, const float* __restrict__ b2,
    float* __restrict__ ws, int layer) {
  __shared__ float x_lds[E_];
  __shared__ float red[256];
  __shared__ float4 racc[256];
  block_ln(ws + WS_HRES, ws + WS_WO,
           ln1s + (size_t)layer * E_, ln1b + (size_t)layer * E_, 1e-6f, x_lds, red);
  int t = threadIdx.x;
  if (blockIdx.x == 0) {
#pragma unroll
    for (int j = 0; j < 4; ++j) {
      ws[WS_HA + t * 4 + j] = x_lds[t * 4 + j];
      ws[WS_FFO + t * 4 + j] = b2[(size_t)layer * E_ + t * 4 + j];
    }
  }
  int tile = blockIdx.x & 15, rowc = blockIdx.x >> 4;
  gemv_acc(W1 + (size_t)layer * E_ * E_, x_lds, ws + WS_FFT, tile * 64, rowc * 128, racc);
}

// grid 128: ff_out += relu(ff_t) @ W2; block0 inits next layer's qkv with biases
__global__ __launch_bounds__(256) void k_w2(
    const float* __restrict__ W2, const float* __restrict__ bq,
    const float* __restrict__ bk, const float* __restrict__ bv,
    float* __restrict__ ws, int layer, int last) {
  __shared__ float x_lds[E_];
  __shared__ float4 racc[256];
  int t = threadIdx.x;
#pragma unroll
  for (int j = 0; j < 4; ++j) x_lds[t * 4 + j] = fmaxf(ws[WS_FFT + t * 4 + j], 0.f);
  __syncthreads();
  if (!last && blockIdx.x == 0) {
    int nl = layer + 1;
#pragma unroll
    for (int j = 0; j < 4; ++j) {
      ws[WS_QKV + t * 4 + j]            = bq[(size_t)nl * E_ + t * 4 + j];
      ws[WS_QKV + E_ + t * 4 + j]       = bk[(size_t)nl * E_ + t * 4 + j];
      ws[WS_QKV + 2 * E_ + t * 4 + j]   = bv[(size_t)nl * E_ + t * 4 + j];
    }
  }
  int tile = blockIdx.x & 15, rowc = blockIdx.x >> 4;
  gemv_acc(W2 + (size_t)layer * E_ * E_, x_lds, ws + WS_FFO, tile * 64, rowc * 128, racc);
}

__global__ __launch_bounds__(256) void k_final(
    const float* __restrict__ ln2s, const float* __restrict__ ln2b,
    const float* __restrict__ Wpi, const float* __restrict__ bpi,
    const float* __restrict__ Wvh, const float* __restrict__ bvh,
    const float* __restrict__ Wc, const float* __restrict__ bc,
    float* __restrict__ ws, float* __restrict__ out) {
  __shared__ float x_lds[E_];
  __shared__ float red[256];
  block_ln(ws + WS_HA, ws + WS_FFO,
           ln2s + (size_t)(L_ - 1) * E_, ln2b + (size_t)(L_ - 1) * E_, 1e-6f, x_lds, red);
  int t = threadIdx.x, wv = t >> 6, lane = t & 63;
  for (int j = wv; j < 47; j += 4) {
    const float* W; int nc, cj; float bb;
    if (j < 32)      { W = Wpi; nc = 32; cj = j;      bb = bpi[cj]; }
    else if (j < 39) { W = Wvh; nc = 7;  cj = j - 32; bb = bvh[cj]; }
    else             { W = Wc;  nc = 8;  cj = j - 39; bb = bc[cj]; }
    float a = 0.f;
#pragma unroll
    for (int it = 0; it < 16; ++it) {
      int k = lane * 16 + it;
      a += x_lds[k] * W[(size_t)k * nc + cj];
    }
    a += __shfl_xor(a, 1);  a += __shfl_xor(a, 2);  a += __shfl_xor(a, 4);
    a += __shfl_xor(a, 8);  a += __shfl_xor(a, 16); a += __shfl_xor(a, 32);
    if (lane == 0) out[j] = a + bb;
  }
}

extern "C" void kernel_launch(void* const* d_in, const int* in_sizes, int n_in,
                              void* d_out, int out_size, void* d_ws, size_t ws_size,
                              hipStream_t stream) {
  (void)in_sizes; (void)n_in; (void)out_size; (void)ws_size;
  const int*   xi     = (const int*)d_in[0];
  const float* cache1 = (const float*)d_in[1];
  const float* cache2 = (const float*)d_in[2];
  const float* emb_type = (const float*)d_in[3];
  const float* emb_id   = (const float*)d_in[4];
  const float* emb_x    = (const float*)d_in[5];
  const float* emb_y    = (const float*)d_in[6];
  const float* emb_t    = (const float*)d_in[7];
  const float* ln_emb_s = (const float*)d_in[8];
  const float* ln_emb_b = (const float*)d_in[9];
  const float* Wv = (const float*)d_in[10];
  const float* Wq = (const float*)d_in[11];
  const float* Wk = (const float*)d_in[12];
  const float* Wo = (const float*)d_in[13];
  const float* W1 = (const float*)d_in[14];
  const float* W2 = (const float*)d_in[15];
  const float* bv = (const float*)d_in[16];
  const float* bq = (const float*)d_in[17];
  const float* bk = (const float*)d_in[18];
  const float* bo = (const float*)d_in[19];
  const float* b1 = (const float*)d_in[20];
  const float* b2 = (const float*)d_in[21];
  const float* ln1_s = (const float*)d_in[22];
  const float* ln1_b = (const float*)d_in[23];
  const float* ln2_s = (const float*)d_in[24];
  const float* ln2_b = (const float*)d_in[25];
  const float* W_pi = (const float*)d_in[26];
  const float* b_pi = (const float*)d_in[27];
  const float* W_vh = (const float*)d_in[28];
  const float* b_vh = (const float*)d_in[29];
  const float* W_c  = (const float*)d_in[30];
  const float* b_c  = (const float*)d_in[31];

  float* out = (float*)d_out;
  float* ws  = (float*)d_ws;
  float* oc1 = out + 47;
  float* oc2 = out + 47 + (size_t)L_ * S_ * E_;

  k_embed<<<1, 256, 0, stream>>>(xi, emb_type, emb_id, emb_x, emb_y, emb_t,
                                 ln_emb_s, ln_emb_b, bq, bk, bv, ws);
  for (int i = 0; i < L_; ++i) {
    const float* pl2s = (i == 0) ? nullptr : ln2_s + (size_t)(i - 1) * E_;
    const float* pl2b = (i == 0) ? nullptr : ln2_b + (size_t)(i - 1) * E_;
    k_qkv<<<384, 256, 0, stream>>>(Wq, Wk, Wv, pl2s, pl2b, ws, i, i == 0 ? 1 : 0);
    k_attn<<<NCHUNK, 256, 0, stream>>>(cache1, cache2, oc1, oc2, ws, i);
    k_combine<<<H_, 256, 0, stream>>>(bo, ws, i);
    k_wo<<<128, 256, 0, stream>>>(Wo, b1, ws, i);
    k_w1<<<128, 256, 0, stream>>>(W1, ln1_s, ln1_b, b2, ws, i);
    k_w2<<<128, 256, 0, stream>>>(W2, bq, bk, bv, ws, i, i == L_ - 1 ? 1 : 0);
  }
  k_final<<<1, 256, 0, stream>>>(ln2_s, ln2_b, W_pi, b_pi, W_vh, b_vh, W_c, b_c, ws, out);
}